// Round 1
// baseline (382.486 us; speedup 1.0000x reference)
//
#include <hip/hip_runtime.h>

// Problem constants (from reference)
#define B 32
#define T 2048
#define D 1024          // D_TOKEN == N_HEADS * D_HEAD

constexpr int TCHUNK = 64;           // tokens per block in the reduction
constexpr int NTC    = T / TCHUNK;   // 32 t-chunks per batch

// ---------------------------------------------------------------------------
// Kernel 1: s[b,d] = sum_t x[b,t,d]
// grid = B * NTC blocks, 256 threads; thread i owns d = 4i..4i+3 (float4).
// Coalesced 16 B/lane streaming reads; partial sums atomically merged into s.
// ---------------------------------------------------------------------------
__global__ __launch_bounds__(256) void reduce_tokens(const float* __restrict__ x,
                                                     float* __restrict__ s) {
    const int blk = blockIdx.x;
    const int b   = blk >> 5;          // blk / NTC   (NTC == 32)
    const int tc  = blk & (NTC - 1);   // blk % NTC
    const int d4  = threadIdx.x * 4;

    const float* base = x + ((size_t)b * T + (size_t)tc * TCHUNK) * D + d4;

    float4 acc = make_float4(0.f, 0.f, 0.f, 0.f);
    #pragma unroll 8
    for (int t = 0; t < TCHUNK; ++t) {
        float4 v = *(const float4*)(base + (size_t)t * D);
        acc.x += v.x; acc.y += v.y; acc.z += v.z; acc.w += v.w;
    }

    float* sp = s + b * D + d4;
    atomicAdd(sp + 0, acc.x);
    atomicAdd(sp + 1, acc.y);
    atomicAdd(sp + 2, acc.z);
    atomicAdd(sp + 3, acc.w);
}

// ---------------------------------------------------------------------------
// Kernels 2 & 3: out[b,c] = sum_d A[b,d] * W[c,d]  (+ bias[c])
// One 64-lane wave per output element. 4 waves/block -> 8192 blocks.
// Global wave id g: b = g & 31, c = g >> 5  => the 32 waves sharing a weight
// row W[c,:] are adjacent in the grid (L2 reuse of the 4 KB row).
// ---------------------------------------------------------------------------
__global__ __launch_bounds__(256) void gemv32(const float* __restrict__ A,
                                              const float* __restrict__ W,
                                              const float* __restrict__ bias,
                                              float* __restrict__ out,
                                              int has_bias) {
    const int g    = blockIdx.x * 4 + (threadIdx.x >> 6);
    const int lane = threadIdx.x & 63;
    const int b    = g & (B - 1);
    const int c    = g >> 5;

    const float* a = A + (size_t)b * D;
    const float* w = W + (size_t)c * D;

    float acc = 0.f;
    #pragma unroll
    for (int k = 0; k < 4; ++k) {
        const int d = k * 256 + lane * 4;
        float4 av = *(const float4*)(a + d);
        float4 wv = *(const float4*)(w + d);
        acc += av.x * wv.x + av.y * wv.y + av.z * wv.z + av.w * wv.w;
    }

    #pragma unroll
    for (int off = 32; off > 0; off >>= 1)
        acc += __shfl_xor(acc, off, 64);

    if (lane == 0) {
        float r = acc;
        if (has_bias) r += bias[c];
        out[(size_t)b * D + c] = r;
    }
}

extern "C" void kernel_launch(void* const* d_in, const int* in_sizes, int n_in,
                              void* d_out, int out_size, void* d_ws, size_t ws_size,
                              hipStream_t stream) {
    const float* x  = (const float*)d_in[0];  // [B, T, D]
    const float* Wh = (const float*)d_in[1];  // [N, Dh, D] == [D, D] flat (c = n*64+h)
    const float* Wp = (const float*)d_in[2];  // [D, D]
    const float* bp = (const float*)d_in[3];  // [D]
    float* out = (float*)d_out;               // [B, D]

    float* s   = (float*)d_ws;                // [B, D] token sums
    float* tmp = s + B * D;                   // [B, D] concat-head activations

    // ws is re-poisoned to 0xAA before every launch -> zero s ourselves.
    hipMemsetAsync(s, 0, (size_t)B * D * sizeof(float), stream);

    reduce_tokens<<<B * NTC, 256, 0, stream>>>(x, s);
    gemv32<<<(B * D) / 4, 256, 0, stream>>>(s,   Wh, nullptr, tmp, 0);
    gemv32<<<(B * D) / 4, 256, 0, stream>>>(tmp, Wp, bp,      out, 1);
}

// Round 2
// 380.978 us; speedup vs baseline: 1.0040x; 1.0040x over previous
//
#include <hip/hip_runtime.h>

// Problem constants (from reference)
#define B 32
#define T 2048
#define D 1024          // D_TOKEN == N_HEADS * D_HEAD

constexpr int TCHUNK = 64;           // tokens per block in the partial reduction
constexpr int NTC    = T / TCHUNK;   // 32 t-chunks per batch

// ---------------------------------------------------------------------------
// Kernel 1: p[b,tc,d] = sum_{t in chunk tc} x[b,t,d]
// grid = B * NTC = 1024 blocks (4/CU), 256 threads; thread i owns d = 4i..4i+3.
// Pure streaming: each block reads 256 KB contiguous, writes 4 KB. No atomics.
// ---------------------------------------------------------------------------
__global__ __launch_bounds__(256) void reduce_tokens_partial(const float* __restrict__ x,
                                                             float* __restrict__ p) {
    const int blk = blockIdx.x;
    const int b   = blk >> 5;          // blk / NTC   (NTC == 32)
    const int tc  = blk & (NTC - 1);   // blk % NTC
    const int d4  = threadIdx.x * 4;

    const float* base = x + ((size_t)b * T + (size_t)tc * TCHUNK) * D + d4;

    float4 acc = make_float4(0.f, 0.f, 0.f, 0.f);
    #pragma unroll 8
    for (int t = 0; t < TCHUNK; ++t) {
        float4 v = *(const float4*)(base + (size_t)t * D);
        acc.x += v.x; acc.y += v.y; acc.z += v.z; acc.w += v.w;
    }

    *(float4*)(p + ((size_t)b * NTC + tc) * D + d4) = acc;
}

// ---------------------------------------------------------------------------
// Kernel 2: s[b,d] = sum_tc p[b,tc,d]   (4 MB read, 128 KB write)
// grid = 128 blocks x 256 threads; thread owns one (b,d). Coalesced.
// ---------------------------------------------------------------------------
__global__ __launch_bounds__(256) void reduce_partials(const float* __restrict__ p,
                                                       float* __restrict__ s) {
    const int b = blockIdx.x >> 2;                     // 4 blocks per batch
    const int d = (blockIdx.x & 3) * 256 + threadIdx.x;

    const float* pp = p + (size_t)b * NTC * D + d;
    float acc = 0.f;
    #pragma unroll
    for (int tc = 0; tc < NTC; ++tc)
        acc += pp[(size_t)tc * D];
    s[(size_t)b * D + d] = acc;
}

// ---------------------------------------------------------------------------
// Kernels 3 & 4: out[b,c] = sum_d A[b,d] * W[c,d]  (+ bias[c])
// One 64-lane wave per (c, 4-batch group): W row loaded once, reused for 4 b's.
// 8 b-groups x 1024 c = 8192 waves -> 2048 blocks of 4 waves.
// Waves sharing W[c,:] are adjacent in the grid (L2 reuse).
// ---------------------------------------------------------------------------
__global__ __launch_bounds__(256) void gemv_b4(const float* __restrict__ A,
                                               const float* __restrict__ W,
                                               const float* __restrict__ bias,
                                               float* __restrict__ out,
                                               int has_bias) {
    const int g    = blockIdx.x * 4 + (threadIdx.x >> 6);
    const int lane = threadIdx.x & 63;
    const int b0   = (g & 7) * 4;      // batch group of 4
    const int c    = g >> 3;

    const float* w  = W + (size_t)c * D;
    const float* a0 = A + (size_t)b0 * D;

    float acc0 = 0.f, acc1 = 0.f, acc2 = 0.f, acc3 = 0.f;
    #pragma unroll
    for (int k = 0; k < 4; ++k) {
        const int d = k * 256 + lane * 4;
        float4 wv = *(const float4*)(w + d);
        float4 a;
        a = *(const float4*)(a0 + d);
        acc0 += a.x * wv.x + a.y * wv.y + a.z * wv.z + a.w * wv.w;
        a = *(const float4*)(a0 + D + d);
        acc1 += a.x * wv.x + a.y * wv.y + a.z * wv.z + a.w * wv.w;
        a = *(const float4*)(a0 + 2 * D + d);
        acc2 += a.x * wv.x + a.y * wv.y + a.z * wv.z + a.w * wv.w;
        a = *(const float4*)(a0 + 3 * D + d);
        acc3 += a.x * wv.x + a.y * wv.y + a.z * wv.z + a.w * wv.w;
    }

    #pragma unroll
    for (int off = 32; off > 0; off >>= 1) {
        acc0 += __shfl_xor(acc0, off, 64);
        acc1 += __shfl_xor(acc1, off, 64);
        acc2 += __shfl_xor(acc2, off, 64);
        acc3 += __shfl_xor(acc3, off, 64);
    }

    if (lane == 0) {
        const float bb = has_bias ? bias[c] : 0.f;
        out[(size_t)(b0 + 0) * D + c] = acc0 + bb;
        out[(size_t)(b0 + 1) * D + c] = acc1 + bb;
        out[(size_t)(b0 + 2) * D + c] = acc2 + bb;
        out[(size_t)(b0 + 3) * D + c] = acc3 + bb;
    }
}

extern "C" void kernel_launch(void* const* d_in, const int* in_sizes, int n_in,
                              void* d_out, int out_size, void* d_ws, size_t ws_size,
                              hipStream_t stream) {
    const float* x  = (const float*)d_in[0];  // [B, T, D]
    const float* Wh = (const float*)d_in[1];  // [N, Dh, D] == [D, D] flat (c = n*64+h)
    const float* Wp = (const float*)d_in[2];  // [D, D]
    const float* bp = (const float*)d_in[3];  // [D]
    float* out = (float*)d_out;               // [B, D]

    float* p   = (float*)d_ws;                // [B, NTC, D] partial token sums (4 MB)
    float* s   = p + (size_t)B * NTC * D;     // [B, D] token sums
    float* tmp = s + (size_t)B * D;           // [B, D] concat-head activations

    reduce_tokens_partial<<<B * NTC, 256, 0, stream>>>(x, p);
    reduce_partials<<<128, 256, 0, stream>>>(p, s);
    gemv_b4<<<(B / 4) * D / 4, 256, 0, stream>>>(s,   Wh, nullptr, tmp, 0);
    gemv_b4<<<(B / 4) * D / 4, 256, 0, stream>>>(tmp, Wp, bp,      out, 1);
}